// Round 1
// baseline (431.536 us; speedup 1.0000x reference)
//
#include <hip/hip_runtime.h>
#include <hip/hip_bf16.h>
#include <math.h>

typedef __bf16 bf16;
typedef __attribute__((ext_vector_type(8))) __bf16 bf16x8;
typedef __attribute__((ext_vector_type(4))) float f32x4;

#define DEV __device__ __forceinline__

// ---------------------------------------------------------------------------
// async global->LDS, 16B per lane. LDS dest is wave-uniform base + lane*16.
DEV void gload16(const void* g, void* l) {
    __builtin_amdgcn_global_load_lds(
        (__attribute__((address_space(1))) void*)(void*)g,
        (__attribute__((address_space(3))) void*)l, 16, 0, 0);
}

// ---------------------------------------------------------------------------
// fp32 -> bf16 conversion, 8 elems/thread, grid-stride
__global__ __launch_bounds__(256) void cvt_kernel(const float* __restrict__ in,
                                                  bf16* __restrict__ out, int n8) {
    for (int i = blockIdx.x * 256 + threadIdx.x; i < n8; i += gridDim.x * 256) {
        const float4* p = (const float4*)(in + (size_t)i * 8);
        float4 a = p[0], b = p[1];
        bf16x8 o;
        o[0] = (bf16)a.x; o[1] = (bf16)a.y; o[2] = (bf16)a.z; o[3] = (bf16)a.w;
        o[4] = (bf16)b.x; o[5] = (bf16)b.y; o[6] = (bf16)b.z; o[7] = (bf16)b.w;
        *(bf16x8*)(out + (size_t)i * 8) = o;
    }
}

// ---------------------------------------------------------------------------
// C[M,N] = A[M,K] @ B[N,K]^T, bf16 in, fp32 accum, bf16 or fp32 out.
// 128x128 tile, BK=64, 4 waves (2x2), 16x16x32 MFMA.
// LDS linear [128][64] bf16 per matrix; XOR swizzle (row&7)<<4 applied via
// pre-swizzled global source (global_load_lds dest must stay linear).
template <bool F32OUT>
__global__ __launch_bounds__(256) void gemm_bt(const bf16* __restrict__ A,
                                               const bf16* __restrict__ B,
                                               void* __restrict__ Cout,
                                               int M, int N, int K) {
    __shared__ __align__(16) bf16 As[128 * 64];
    __shared__ __align__(16) bf16 Bs[128 * 64];
    const int tid = threadIdx.x, lane = tid & 63, wv = tid >> 6;
    const int tm = blockIdx.y * 128, tn = blockIdx.x * 128;
    const int wr = (wv >> 1) * 64, wc = (wv & 1) * 64;

    f32x4 acc[4][4] = {};

    const int scb = (lane & 7) * 16;  // lds col-byte of this lane's 16B chunk

    for (int k0 = 0; k0 < K; k0 += 64) {
#pragma unroll
        for (int i = 0; i < 4; ++i) {
            int chunk = wv * 4 + i;                 // 16 chunks of 1024B per tile
            int row = chunk * 8 + (lane >> 3);      // [128][64] bf16 = 128B rows
            int cb = scb ^ ((row & 7) << 4);        // pre-swizzled source col
            gload16((const char*)(A + (size_t)(tm + row) * K + k0) + cb,
                    (char*)As + chunk * 1024);
            gload16((const char*)(B + (size_t)(tn + row) * K + k0) + cb,
                    (char*)Bs + chunk * 1024);
        }
        __syncthreads();
#pragma unroll
        for (int kk = 0; kk < 2; ++kk) {
            bf16x8 af[4], bfr[4];
#pragma unroll
            for (int m = 0; m < 4; ++m) {
                int row = wr + m * 16 + (lane & 15);
                int cb = (kk * 64 + ((lane >> 4) * 16)) ^ ((row & 7) << 4);
                af[m] = *(const bf16x8*)((const char*)As + row * 128 + cb);
            }
#pragma unroll
            for (int n = 0; n < 4; ++n) {
                int row = wc + n * 16 + (lane & 15);
                int cb = (kk * 64 + ((lane >> 4) * 16)) ^ ((row & 7) << 4);
                bfr[n] = *(const bf16x8*)((const char*)Bs + row * 128 + cb);
            }
#pragma unroll
            for (int m = 0; m < 4; ++m)
#pragma unroll
                for (int n = 0; n < 4; ++n)
                    acc[m][n] = __builtin_amdgcn_mfma_f32_16x16x32_bf16(
                        af[m], bfr[n], acc[m][n], 0, 0, 0);
        }
        __syncthreads();
    }
#pragma unroll
    for (int m = 0; m < 4; ++m)
#pragma unroll
        for (int n = 0; n < 4; ++n)
#pragma unroll
            for (int r = 0; r < 4; ++r) {
                int row = tm + wr + m * 16 + (lane >> 4) * 4 + r;
                int col = tn + wc + n * 16 + (lane & 15);
                if (F32OUT)
                    ((float*)Cout)[(size_t)row * N + col] = acc[m][n][r];
                else
                    ((bf16*)Cout)[(size_t)row * N + col] = (bf16)acc[m][n][r];
            }
}

// ---------------------------------------------------------------------------
// RoPE + RMSNorm(*1.2), in-place on bf16 q or k. One wave per (row, head).
// layout: [4096 rows][16 heads][128], half = 64. blockIdx.y: 0 = q, 1 = k.
__global__ __launch_bounds__(256) void rope_rms(bf16* __restrict__ q,
                                                bf16* __restrict__ k,
                                                const float* __restrict__ cosp,
                                                const float* __restrict__ sinp) {
    int gw = blockIdx.x * 4 + (threadIdx.x >> 6);
    int lane = threadIdx.x & 63;
    bf16* base = (blockIdx.y == 0) ? q : k;
    int m = gw >> 4, h = gw & 15;
    int s = m & 2047;  // m = b*S + s, S = 2048
    bf16* p = base + (size_t)m * 2048 + h * 128;
    float x1 = (float)p[lane], x2 = (float)p[lane + 64];
    float c = cosp[s * 64 + lane], si = sinp[s * 64 + lane];
    float r1 = x1 * c + x2 * si;
    float r2 = x2 * c - x1 * si;
    float ss = r1 * r1 + r2 * r2;
#pragma unroll
    for (int msk = 1; msk < 64; msk <<= 1) ss += __shfl_xor(ss, msk);
    float sc = rsqrtf(ss * (1.0f / 128.0f) + 1.1920928955078125e-07f) * 1.2f;
    p[lane] = (bf16)(r1 * sc);
    p[lane + 64] = (bf16)(r2 * sc);
}

// ---------------------------------------------------------------------------
// Flash attention fwd. grid = (S/64, B*H), 256 threads (4 waves).
// Each wave owns 16 q rows; KV tiles of 64. No mask.
__global__ __launch_bounds__(256) void attn_kernel(const bf16* __restrict__ q,
                                                   const bf16* __restrict__ k,
                                                   const bf16* __restrict__ v,
                                                   bf16* __restrict__ y) {
    __shared__ __align__(16) bf16 Ks[64][136];    // key-major, +8 pad
    __shared__ __align__(16) bf16 Vt[128][72];    // transposed V, +8 pad
    __shared__ __align__(16) bf16 Ps[4][16][72];  // per-wave P tile

    const int lane = threadIdx.x & 63, wv = threadIdx.x >> 6;
    const int bh = blockIdx.y, b = bh >> 4, h = bh & 15;
    const int q0 = blockIdx.x * 64;
    const size_t headoff = (size_t)h * 128;

    // Q fragments in registers: row = lane&15 (within wave's 16), k contiguous
    const bf16* qrow = q + (size_t)(b * 2048 + q0 + wv * 16 + (lane & 15)) * 2048 +
                       headoff + (lane >> 4) * 8;
    bf16x8 qf[4];
#pragma unroll
    for (int kk = 0; kk < 4; ++kk) qf[kk] = *(const bf16x8*)(qrow + kk * 32);

    float mrow[4] = {-INFINITY, -INFINITY, -INFINITY, -INFINITY};
    float lrow[4] = {0.f, 0.f, 0.f, 0.f};
    f32x4 acco[8] = {};

    const int srow = threadIdx.x >> 2;        // staging: 4 threads per kv row
    const int scc = (threadIdx.x & 3) * 32;   // 32 cols each
    const bf16* kbase = k + (size_t)(b * 2048 + srow) * 2048 + headoff + scc;
    const bf16* vbase = v + (size_t)(b * 2048 + srow) * 2048 + headoff + scc;
    const float scale = 0.08838834764831845f;  // 1/sqrt(128)

    for (int kt = 0; kt < 2048; kt += 64) {
#pragma unroll
        for (int i = 0; i < 4; ++i) {
            bf16x8 t = *(const bf16x8*)(kbase + (size_t)kt * 2048 + i * 8);
            *(bf16x8*)(&Ks[srow][scc + i * 8]) = t;
            bf16x8 u = *(const bf16x8*)(vbase + (size_t)kt * 2048 + i * 8);
#pragma unroll
            for (int j = 0; j < 8; ++j) Vt[scc + i * 8 + j][srow] = u[j];
        }
        __syncthreads();

        // QK^T: scores[16 q][64 keys] per wave, 4 col-fragments
        f32x4 sc[4];
#pragma unroll
        for (int kc = 0; kc < 4; ++kc) {
            f32x4 a = {};
#pragma unroll
            for (int kk = 0; kk < 4; ++kk) {
                const bf16x8 kf = *(const bf16x8*)(
                    &Ks[kc * 16 + (lane & 15)][kk * 32 + (lane >> 4) * 8]);
                a = __builtin_amdgcn_mfma_f32_16x16x32_bf16(qf[kk], kf, a, 0, 0, 0);
            }
            sc[kc] = a;
        }

        // online softmax: row = (lane>>4)*4 + r, cols spread over lane&15 and kc
        float alpha[4];
#pragma unroll
        for (int r = 0; r < 4; ++r) {
            float s0 = sc[0][r] * scale, s1 = sc[1][r] * scale;
            float s2 = sc[2][r] * scale, s3 = sc[3][r] * scale;
            float tmax = fmaxf(fmaxf(s0, s1), fmaxf(s2, s3));
#pragma unroll
            for (int msk = 1; msk <= 8; msk <<= 1)
                tmax = fmaxf(tmax, __shfl_xor(tmax, msk));
            float mn = fmaxf(mrow[r], tmax);
            float al = __expf(mrow[r] - mn);
            mrow[r] = mn;
            alpha[r] = al;
            float p0 = __expf(s0 - mn), p1 = __expf(s1 - mn);
            float p2 = __expf(s2 - mn), p3 = __expf(s3 - mn);
            int prow = (lane >> 4) * 4 + r, pcol = lane & 15;
            Ps[wv][prow][pcol] = (bf16)p0;
            Ps[wv][prow][pcol + 16] = (bf16)p1;
            Ps[wv][prow][pcol + 32] = (bf16)p2;
            Ps[wv][prow][pcol + 48] = (bf16)p3;
            float rs = p0 + p1 + p2 + p3;
#pragma unroll
            for (int msk = 1; msk <= 8; msk <<= 1) rs += __shfl_xor(rs, msk);
            lrow[r] = lrow[r] * al + rs;
        }
#pragma unroll
        for (int dc = 0; dc < 8; ++dc) {
            acco[dc][0] *= alpha[0];
            acco[dc][1] *= alpha[1];
            acco[dc][2] *= alpha[2];
            acco[dc][3] *= alpha[3];
        }
        // drain our own ds_writes of Ps before reading them cross-lane
        asm volatile("s_waitcnt lgkmcnt(0)" ::: "memory");

        // PV: out[16 q][128 d] += P[16][64] @ V[64][128]
#pragma unroll
        for (int kk2 = 0; kk2 < 2; ++kk2) {
            const bf16x8 pa = *(const bf16x8*)(
                &Ps[wv][lane & 15][kk2 * 32 + (lane >> 4) * 8]);
#pragma unroll
            for (int dc = 0; dc < 8; ++dc) {
                const bf16x8 vb = *(const bf16x8*)(
                    &Vt[dc * 16 + (lane & 15)][kk2 * 32 + (lane >> 4) * 8]);
                acco[dc] = __builtin_amdgcn_mfma_f32_16x16x32_bf16(pa, vb, acco[dc], 0, 0, 0);
            }
        }
        __syncthreads();
    }

    float inv[4];
#pragma unroll
    for (int r = 0; r < 4; ++r) inv[r] = 1.0f / lrow[r];
#pragma unroll
    for (int dc = 0; dc < 8; ++dc)
#pragma unroll
        for (int r = 0; r < 4; ++r) {
            int row = q0 + wv * 16 + (lane >> 4) * 4 + r;
            int col = (int)headoff + dc * 16 + (lane & 15);
            y[(size_t)(b * 2048 + row) * 2048 + col] = (bf16)(acco[dc][r] * inv[r]);
        }
}

// ---------------------------------------------------------------------------
extern "C" void kernel_launch(void* const* d_in, const int* in_sizes, int n_in,
                              void* d_out, int out_size, void* d_ws, size_t ws_size,
                              hipStream_t stream) {
    const float* x = (const float*)d_in[0];
    const float* cs = (const float*)d_in[1];
    const float* sn = (const float*)d_in[2];
    const float* Wq = (const float*)d_in[3];
    const float* Wk = (const float*)d_in[4];
    const float* Wv = (const float*)d_in[5];
    const float* Wo = (const float*)d_in[6];

    char* ws = (char*)d_ws;
    bf16* xb  = (bf16*)(ws + 0);          // 4096x2048
    bf16* wqb = (bf16*)(ws + 16777216);   // 2048x2048
    bf16* wkb = (bf16*)(ws + 25165824);
    bf16* wvb = (bf16*)(ws + 33554432);
    bf16* wob = (bf16*)(ws + 41943040);
    bf16* qb  = (bf16*)(ws + 50331648);   // 4096x2048
    bf16* kb  = (bf16*)(ws + 67108864);
    bf16* vb  = (bf16*)(ws + 83886080);
    bf16* yb  = (bf16*)(ws + 100663296);

    cvt_kernel<<<1024, 256, 0, stream>>>(x, xb, 8388608 / 8);
    cvt_kernel<<<512, 256, 0, stream>>>(Wq, wqb, 4194304 / 8);
    cvt_kernel<<<512, 256, 0, stream>>>(Wk, wkb, 4194304 / 8);
    cvt_kernel<<<512, 256, 0, stream>>>(Wv, wvb, 4194304 / 8);
    cvt_kernel<<<512, 256, 0, stream>>>(Wo, wob, 4194304 / 8);

    dim3 g(16, 32);  // N/128, M/128
    gemm_bt<false><<<g, 256, 0, stream>>>(xb, wqb, qb, 4096, 2048, 2048);
    gemm_bt<false><<<g, 256, 0, stream>>>(xb, wkb, kb, 4096, 2048, 2048);
    gemm_bt<false><<<g, 256, 0, stream>>>(xb, wvb, vb, 4096, 2048, 2048);

    rope_rms<<<dim3(16384, 2), 256, 0, stream>>>(qb, kb, cs, sn);

    attn_kernel<<<dim3(32, 32), 256, 0, stream>>>(qb, kb, vb, yb);

    gemm_bt<true><<<g, 256, 0, stream>>>(yb, wob, d_out, 4096, 2048, 2048);
}

// Round 2
// 351.841 us; speedup vs baseline: 1.2265x; 1.2265x over previous
//
#include <hip/hip_runtime.h>
#include <hip/hip_bf16.h>
#include <math.h>

typedef __bf16 bf16;
typedef __attribute__((ext_vector_type(8))) __bf16 bf16x8;
typedef __attribute__((ext_vector_type(4))) float f32x4;

#define DEV __device__ __forceinline__

// ---------------------------------------------------------------------------
// async global->LDS, 16B per lane. LDS dest is wave-uniform base + lane*16.
DEV void gload16(const void* g, void* l) {
    __builtin_amdgcn_global_load_lds(
        (__attribute__((address_space(1))) void*)(void*)g,
        (__attribute__((address_space(3))) void*)l, 16, 0, 0);
}

DEV unsigned pk2(float a, float b) {
    union { bf16 h[2]; unsigned u; } z;
    z.h[0] = (bf16)a; z.h[1] = (bf16)b;
    return z.u;
}

// ---------------------------------------------------------------------------
// fp32 -> bf16 conversion, 8 elems/thread, grid-stride
__global__ __launch_bounds__(256) void cvt_kernel(const float* __restrict__ in,
                                                  bf16* __restrict__ out, int n8) {
    for (int i = blockIdx.x * 256 + threadIdx.x; i < n8; i += gridDim.x * 256) {
        const float4* p = (const float4*)(in + (size_t)i * 8);
        float4 a = p[0], b = p[1];
        bf16x8 o;
        o[0] = (bf16)a.x; o[1] = (bf16)a.y; o[2] = (bf16)a.z; o[3] = (bf16)a.w;
        o[4] = (bf16)b.x; o[5] = (bf16)b.y; o[6] = (bf16)b.z; o[7] = (bf16)b.w;
        *(bf16x8*)(out + (size_t)i * 8) = o;
    }
}

// ---------------------------------------------------------------------------
// C[M,N] = A[M,K] @ B[N,K]^T, bf16 in, fp32 accum, bf16 or fp32 out.
// 128x128 tile, BK=64, 4 waves (2x2), 16x16x32 MFMA. (unchanged, passing)
template <bool F32OUT>
__global__ __launch_bounds__(256) void gemm_bt(const bf16* __restrict__ A,
                                               const bf16* __restrict__ B,
                                               void* __restrict__ Cout,
                                               int M, int N, int K) {
    __shared__ __align__(16) bf16 As[128 * 64];
    __shared__ __align__(16) bf16 Bs[128 * 64];
    const int tid = threadIdx.x, lane = tid & 63, wv = tid >> 6;
    const int tm = blockIdx.y * 128, tn = blockIdx.x * 128;
    const int wr = (wv >> 1) * 64, wc = (wv & 1) * 64;

    f32x4 acc[4][4] = {};
    const int scb = (lane & 7) * 16;

    for (int k0 = 0; k0 < K; k0 += 64) {
#pragma unroll
        for (int i = 0; i < 4; ++i) {
            int chunk = wv * 4 + i;
            int row = chunk * 8 + (lane >> 3);
            int cb = scb ^ ((row & 7) << 4);
            gload16((const char*)(A + (size_t)(tm + row) * K + k0) + cb,
                    (char*)As + chunk * 1024);
            gload16((const char*)(B + (size_t)(tn + row) * K + k0) + cb,
                    (char*)Bs + chunk * 1024);
        }
        __syncthreads();
#pragma unroll
        for (int kk = 0; kk < 2; ++kk) {
            bf16x8 af[4], bfr[4];
#pragma unroll
            for (int m = 0; m < 4; ++m) {
                int row = wr + m * 16 + (lane & 15);
                int cb = (kk * 64 + ((lane >> 4) * 16)) ^ ((row & 7) << 4);
                af[m] = *(const bf16x8*)((const char*)As + row * 128 + cb);
            }
#pragma unroll
            for (int n = 0; n < 4; ++n) {
                int row = wc + n * 16 + (lane & 15);
                int cb = (kk * 64 + ((lane >> 4) * 16)) ^ ((row & 7) << 4);
                bfr[n] = *(const bf16x8*)((const char*)Bs + row * 128 + cb);
            }
#pragma unroll
            for (int m = 0; m < 4; ++m)
#pragma unroll
                for (int n = 0; n < 4; ++n)
                    acc[m][n] = __builtin_amdgcn_mfma_f32_16x16x32_bf16(
                        af[m], bfr[n], acc[m][n], 0, 0, 0);
        }
        __syncthreads();
    }
#pragma unroll
    for (int m = 0; m < 4; ++m)
#pragma unroll
        for (int n = 0; n < 4; ++n)
#pragma unroll
            for (int r = 0; r < 4; ++r) {
                int row = tm + wr + m * 16 + (lane >> 4) * 4 + r;
                int col = tn + wc + n * 16 + (lane & 15);
                if (F32OUT)
                    ((float*)Cout)[(size_t)row * N + col] = acc[m][n][r];
                else
                    ((bf16*)Cout)[(size_t)row * N + col] = (bf16)acc[m][n][r];
            }
}

// ---------------------------------------------------------------------------
// RoPE + RMSNorm(*1.2), in-place. (unchanged, passing)
__global__ __launch_bounds__(256) void rope_rms(bf16* __restrict__ q,
                                                bf16* __restrict__ k,
                                                const float* __restrict__ cosp,
                                                const float* __restrict__ sinp) {
    int gw = blockIdx.x * 4 + (threadIdx.x >> 6);
    int lane = threadIdx.x & 63;
    bf16* base = (blockIdx.y == 0) ? q : k;
    int m = gw >> 4, h = gw & 15;
    int s = m & 2047;
    bf16* p = base + (size_t)m * 2048 + h * 128;
    float x1 = (float)p[lane], x2 = (float)p[lane + 64];
    float c = cosp[s * 64 + lane], si = sinp[s * 64 + lane];
    float r1 = x1 * c + x2 * si;
    float r2 = x2 * c - x1 * si;
    float ss = r1 * r1 + r2 * r2;
#pragma unroll
    for (int msk = 1; msk < 64; msk <<= 1) ss += __shfl_xor(ss, msk);
    float sc = rsqrtf(ss * (1.0f / 128.0f) + 1.1920928955078125e-07f) * 1.2f;
    p[lane] = (bf16)(r1 * sc);
    p[lane + 64] = (bf16)(r2 * sc);
}

// ---------------------------------------------------------------------------
// Flash attention fwd, swapped-QK^T in-register-P structure.
// 8 waves x 16 q rows = 128 q/block. KV tile = 64. grid=(16,32), 512 thr.
// K: LDS [64][128] linear, XOR-swizzled via pre-swizzled global_load_lds src.
// V: LDS Vt[128][72] (transposed), staged via coalesced scalar global reads +
//    vector ds_write_b128.  P: registers only (pack + shfl exchange).
__global__ __launch_bounds__(512) void attn_kernel(const bf16* __restrict__ q,
                                                   const bf16* __restrict__ k,
                                                   const bf16* __restrict__ v,
                                                   bf16* __restrict__ y) {
    __shared__ __align__(16) bf16 Ks[64 * 128];
    __shared__ __align__(16) bf16 Vt[128][72];

    const int tid = threadIdx.x, lane = tid & 63, wv = tid >> 6;
    const int hi = lane >> 4, ql = lane & 15;

    // bijective XCD-chunked swizzle: XCD c owns bh in {4c..4c+3}
    int wgid = blockIdx.y * 16 + blockIdx.x;
    int xcd = wgid & 7, j = wgid >> 3;
    int bh = xcd * 4 + (j >> 4);
    int qblk = j & 15;
    const int b = bh >> 4, h = bh & 15;
    const int q0 = qblk * 128;

    // Q fragments in registers: B-operand layout (col=q=ql, k=d contiguous)
    const bf16* qrow = q + (size_t)(b * 2048 + q0 + wv * 16 + ql) * 2048 +
                       h * 128 + hi * 8;
    bf16x8 qf[4];
#pragma unroll
    for (int kk = 0; kk < 4; ++kk) qf[kk] = *(const bf16x8*)(qrow + kk * 32);

    float mrun = -INFINITY, lrun = 0.f;
    f32x4 acco[8] = {};

    // V staging assignment: this thread owns column d, 16 kv rows
    const int dcol = lane + 64 * (wv & 1);
    const int kvg = wv >> 1;  // 0..3 -> kv group of 16
    const bf16* vcol = v + (size_t)(b * 2048) * 2048 + h * 128 + dcol;

    const float scale = 0.08838834764831845f;  // 1/sqrt(128)

    for (int kt = 0; kt < 2048; kt += 64) {
        // ---- K stage: 2 x global_load_lds(16B) per thread, swizzled source
#pragma unroll
        for (int i = 0; i < 2; ++i) {
            int chunk = wv * 2 + i;            // 16 chunks x 1KB
            int row = chunk * 4 + hi;          // kv row (256B rows)
            int cb = ((lane & 15) * 16) ^ ((row & 7) << 4);
            gload16((const char*)(k + (size_t)(b * 2048 + kt + row) * 2048 + h * 128) + cb,
                    (char*)Ks + chunk * 1024);
        }
        // ---- V stage: 16 coalesced scalar reads down column dcol, 2 vec writes
        {
            const bf16* vp = vcol + (size_t)(kt + kvg * 16) * 2048;
            bf16x8 va, vb2;
#pragma unroll
            for (int jj = 0; jj < 8; ++jj) {
                va[jj] = vp[(size_t)jj * 2048];
                vb2[jj] = vp[(size_t)(jj + 8) * 2048];
            }
            *(bf16x8*)(&Vt[dcol][kvg * 16]) = va;
            *(bf16x8*)(&Vt[dcol][kvg * 16 + 8]) = vb2;
        }
        __syncthreads();

        // ---- swapped QK^T: C^T[kv][q], lane holds q=ql, kv=kc*16+4*hi+r
        f32x4 st[4];
#pragma unroll
        for (int kc = 0; kc < 4; ++kc) {
            f32x4 a = {};
#pragma unroll
            for (int kk = 0; kk < 4; ++kk) {
                int row = kc * 16 + ql;
                int cb = (kk * 64 + 16 * hi) ^ ((row & 7) << 4);
                const bf16x8 kf = *(const bf16x8*)((const char*)Ks + row * 256 + cb);
                a = __builtin_amdgcn_mfma_f32_16x16x32_bf16(kf, qf[kk], a, 0, 0, 0);
            }
            st[kc] = a;
        }

        // ---- online softmax, stats per lane for q=ql
        float s[4][4], mx = -INFINITY;
#pragma unroll
        for (int kc = 0; kc < 4; ++kc)
#pragma unroll
            for (int r = 0; r < 4; ++r) {
                s[kc][r] = st[kc][r] * scale;
                mx = fmaxf(mx, s[kc][r]);
            }
        mx = fmaxf(mx, __shfl_xor(mx, 16));
        mx = fmaxf(mx, __shfl_xor(mx, 32));
        float mn = fmaxf(mrun, mx);
        float alpha = __expf(mrun - mn);
        mrun = mn;
        float p[4][4], rs = 0.f;
#pragma unroll
        for (int kc = 0; kc < 4; ++kc)
#pragma unroll
            for (int r = 0; r < 4; ++r) {
                p[kc][r] = __expf(s[kc][r] - mn);
                rs += p[kc][r];
            }
        rs += __shfl_xor(rs, 16);
        rs += __shfl_xor(rs, 32);
        lrun = lrun * alpha + rs;

        // rescale O (alpha for O-row q=4*hi+r lives in lane 4*hi+r)
        float al[4];
#pragma unroll
        for (int r = 0; r < 4; ++r) al[r] = __shfl(alpha, hi * 4 + r);
#pragma unroll
        for (int dc = 0; dc < 8; ++dc) {
            acco[dc][0] *= al[0];
            acco[dc][1] *= al[1];
            acco[dc][2] *= al[2];
            acco[dc][3] *= al[3];
        }

        // ---- pack P to bf16 pairs: pk[kc][0]=kv{+0,+1}, pk[kc][1]=kv{+2,+3}
        unsigned pk[4][2];
#pragma unroll
        for (int kc = 0; kc < 4; ++kc) {
            pk[kc][0] = pk2(p[kc][0], p[kc][1]);
            pk[kc][1] = pk2(p[kc][2], p[kc][3]);
        }

        // ---- exchange into PV A-frags: lane needs kv=32*kk2+8*hi+0..7,
        // owned by lanes (q, hi'=2(hi&1)) and (q, hi''=2(hi&1)+1) at
        // kc' = 2*kk2 + (hi>>1).
        const int s1 = ql + 16 * (2 * (hi & 1));
        const int s2 = s1 + 16;
        const bool up = hi >= 2;
#pragma unroll
        for (int kk2 = 0; kk2 < 2; ++kk2) {
            unsigned A0 = (unsigned)__shfl((int)pk[2 * kk2][0], s1);
            unsigned A1 = (unsigned)__shfl((int)pk[2 * kk2][1], s1);
            unsigned B0 = (unsigned)__shfl((int)pk[2 * kk2 + 1][0], s1);
            unsigned B1 = (unsigned)__shfl((int)pk[2 * kk2 + 1][1], s1);
            unsigned C0 = (unsigned)__shfl((int)pk[2 * kk2][0], s2);
            unsigned C1 = (unsigned)__shfl((int)pk[2 * kk2][1], s2);
            unsigned D0 = (unsigned)__shfl((int)pk[2 * kk2 + 1][0], s2);
            unsigned D1 = (unsigned)__shfl((int)pk[2 * kk2 + 1][1], s2);
            union { unsigned u[4]; bf16x8 v; } fr;
            fr.u[0] = up ? B0 : A0;
            fr.u[1] = up ? B1 : A1;
            fr.u[2] = up ? D0 : C0;
            fr.u[3] = up ? D1 : C1;
            const bf16x8 pa = fr.v;
            // ---- PV: B-frag = Vt[dc*16+ql][kv], even bank spread (144B rows)
#pragma unroll
            for (int dc = 0; dc < 8; ++dc) {
                const bf16x8 vf = *(const bf16x8*)(&Vt[dc * 16 + ql][kk2 * 32 + hi * 8]);
                acco[dc] = __builtin_amdgcn_mfma_f32_16x16x32_bf16(pa, vf, acco[dc], 0, 0, 0);
            }
        }
        __syncthreads();
    }

    // epilogue: O-row q=4*hi+r, 1/l from lane 4*hi+r
    float linv = 1.0f / lrun;
    float il[4];
#pragma unroll
    for (int r = 0; r < 4; ++r) il[r] = __shfl(linv, hi * 4 + r);
#pragma unroll
    for (int dc = 0; dc < 8; ++dc)
#pragma unroll
        for (int r = 0; r < 4; ++r) {
            int row = q0 + wv * 16 + hi * 4 + r;
            int col = h * 128 + dc * 16 + ql;
            y[(size_t)(b * 2048 + row) * 2048 + col] = (bf16)(acco[dc][r] * il[r]);
        }
}

// ---------------------------------------------------------------------------
extern "C" void kernel_launch(void* const* d_in, const int* in_sizes, int n_in,
                              void* d_out, int out_size, void* d_ws, size_t ws_size,
                              hipStream_t stream) {
    const float* x = (const float*)d_in[0];
    const float* cs = (const float*)d_in[1];
    const float* sn = (const float*)d_in[2];
    const float* Wq = (const float*)d_in[3];
    const float* Wk = (const float*)d_in[4];
    const float* Wv = (const float*)d_in[5];
    const float* Wo = (const float*)d_in[6];

    char* ws = (char*)d_ws;
    bf16* xb  = (bf16*)(ws + 0);          // 4096x2048
    bf16* wqb = (bf16*)(ws + 16777216);   // 2048x2048
    bf16* wkb = (bf16*)(ws + 25165824);
    bf16* wvb = (bf16*)(ws + 33554432);
    bf16* wob = (bf16*)(ws + 41943040);
    bf16* qb  = (bf16*)(ws + 50331648);   // 4096x2048
    bf16* kb  = (bf16*)(ws + 67108864);
    bf16* vb  = (bf16*)(ws + 83886080);
    bf16* yb  = (bf16*)(ws + 100663296);

    cvt_kernel<<<1024, 256, 0, stream>>>(x, xb, 8388608 / 8);
    cvt_kernel<<<512, 256, 0, stream>>>(Wq, wqb, 4194304 / 8);
    cvt_kernel<<<512, 256, 0, stream>>>(Wk, wkb, 4194304 / 8);
    cvt_kernel<<<512, 256, 0, stream>>>(Wv, wvb, 4194304 / 8);
    cvt_kernel<<<512, 256, 0, stream>>>(Wo, wob, 4194304 / 8);

    dim3 g(16, 32);  // N/128, M/128
    gemm_bt<false><<<g, 256, 0, stream>>>(xb, wqb, qb, 4096, 2048, 2048);
    gemm_bt<false><<<g, 256, 0, stream>>>(xb, wkb, kb, 4096, 2048, 2048);
    gemm_bt<false><<<g, 256, 0, stream>>>(xb, wvb, vb, 4096, 2048, 2048);

    rope_rms<<<dim3(16384, 2), 256, 0, stream>>>(qb, kb, cs, sn);

    attn_kernel<<<dim3(16, 32), 512, 0, stream>>>(qb, kb, vb, yb);

    gemm_bt<true><<<g, 256, 0, stream>>>(yb, wob, d_out, 4096, 2048, 2048);
}

// Round 3
// 345.175 us; speedup vs baseline: 1.2502x; 1.0193x over previous
//
#include <hip/hip_runtime.h>
#include <hip/hip_bf16.h>
#include <math.h>

typedef __bf16 bf16;
typedef __attribute__((ext_vector_type(8))) __bf16 bf16x8;
typedef __attribute__((ext_vector_type(4))) float f32x4;
typedef __attribute__((ext_vector_type(16))) float f32x16;

#define DEV __device__ __forceinline__

// ---------------------------------------------------------------------------
// async global->LDS, 16B per lane. LDS dest is wave-uniform base + lane*16.
DEV void gload16(const void* g, void* l) {
    __builtin_amdgcn_global_load_lds(
        (__attribute__((address_space(1))) void*)(void*)g,
        (__attribute__((address_space(3))) void*)l, 16, 0, 0);
}

DEV unsigned pk2(float a, float b) {
    union { bf16 h[2]; unsigned u; } z;
    z.h[0] = (bf16)a; z.h[1] = (bf16)b;
    return z.u;
}

// swap a's hi-32-lane contents with b's lo-32-lane contents:
// a'[l>=32] = b[l-32]; b'[l<32] = a[l+32]; others unchanged.
DEV void plswap(unsigned& a, unsigned& b) {
    asm volatile("v_permlane32_swap_b32 %0, %1" : "+v"(a), "+v"(b));
}

// ---------------------------------------------------------------------------
// fp32 -> bf16 conversion, 8 elems/thread, grid-stride
__global__ __launch_bounds__(256) void cvt_kernel(const float* __restrict__ in,
                                                  bf16* __restrict__ out, int n8) {
    for (int i = blockIdx.x * 256 + threadIdx.x; i < n8; i += gridDim.x * 256) {
        const float4* p = (const float4*)(in + (size_t)i * 8);
        float4 a = p[0], b = p[1];
        bf16x8 o;
        o[0] = (bf16)a.x; o[1] = (bf16)a.y; o[2] = (bf16)a.z; o[3] = (bf16)a.w;
        o[4] = (bf16)b.x; o[5] = (bf16)b.y; o[6] = (bf16)b.z; o[7] = (bf16)b.w;
        *(bf16x8*)(out + (size_t)i * 8) = o;
    }
}

// ---------------------------------------------------------------------------
// C[M,N] = A[M,K] @ B[N,K]^T, bf16 in, fp32 accum, bf16 or fp32 out.
// 128x128 tile, BK=64, 4 waves (2x2), 16x16x32 MFMA. (unchanged, passing)
template <bool F32OUT>
__global__ __launch_bounds__(256) void gemm_bt(const bf16* __restrict__ A,
                                               const bf16* __restrict__ B,
                                               void* __restrict__ Cout,
                                               int M, int N, int K) {
    __shared__ __align__(16) bf16 As[128 * 64];
    __shared__ __align__(16) bf16 Bs[128 * 64];
    const int tid = threadIdx.x, lane = tid & 63, wv = tid >> 6;
    const int tm = blockIdx.y * 128, tn = blockIdx.x * 128;
    const int wr = (wv >> 1) * 64, wc = (wv & 1) * 64;

    f32x4 acc[4][4] = {};
    const int scb = (lane & 7) * 16;

    for (int k0 = 0; k0 < K; k0 += 64) {
#pragma unroll
        for (int i = 0; i < 4; ++i) {
            int chunk = wv * 4 + i;
            int row = chunk * 8 + (lane >> 3);
            int cb = scb ^ ((row & 7) << 4);
            gload16((const char*)(A + (size_t)(tm + row) * K + k0) + cb,
                    (char*)As + chunk * 1024);
            gload16((const char*)(B + (size_t)(tn + row) * K + k0) + cb,
                    (char*)Bs + chunk * 1024);
        }
        __syncthreads();
#pragma unroll
        for (int kk = 0; kk < 2; ++kk) {
            bf16x8 af[4], bfr[4];
#pragma unroll
            for (int m = 0; m < 4; ++m) {
                int row = wr + m * 16 + (lane & 15);
                int cb = (kk * 64 + ((lane >> 4) * 16)) ^ ((row & 7) << 4);
                af[m] = *(const bf16x8*)((const char*)As + row * 128 + cb);
            }
#pragma unroll
            for (int n = 0; n < 4; ++n) {
                int row = wc + n * 16 + (lane & 15);
                int cb = (kk * 64 + ((lane >> 4) * 16)) ^ ((row & 7) << 4);
                bfr[n] = *(const bf16x8*)((const char*)Bs + row * 128 + cb);
            }
#pragma unroll
            for (int m = 0; m < 4; ++m)
#pragma unroll
                for (int n = 0; n < 4; ++n)
                    acc[m][n] = __builtin_amdgcn_mfma_f32_16x16x32_bf16(
                        af[m], bfr[n], acc[m][n], 0, 0, 0);
        }
        __syncthreads();
    }
#pragma unroll
    for (int m = 0; m < 4; ++m)
#pragma unroll
        for (int n = 0; n < 4; ++n)
#pragma unroll
            for (int r = 0; r < 4; ++r) {
                int row = tm + wr + m * 16 + (lane >> 4) * 4 + r;
                int col = tn + wc + n * 16 + (lane & 15);
                if (F32OUT)
                    ((float*)Cout)[(size_t)row * N + col] = acc[m][n][r];
                else
                    ((bf16*)Cout)[(size_t)row * N + col] = (bf16)acc[m][n][r];
            }
}

// ---------------------------------------------------------------------------
// RoPE + RMSNorm(*1.2), in-place. q additionally pre-scaled by
// (1/sqrt(128))*log2(e) so attention scores come out in exp2 domain.
__global__ __launch_bounds__(256) void rope_rms(bf16* __restrict__ q,
                                                bf16* __restrict__ k,
                                                const float* __restrict__ cosp,
                                                const float* __restrict__ sinp) {
    int gw = blockIdx.x * 4 + (threadIdx.x >> 6);
    int lane = threadIdx.x & 63;
    bf16* base = (blockIdx.y == 0) ? q : k;
    int m = gw >> 4, h = gw & 15;
    int s = m & 2047;
    bf16* p = base + (size_t)m * 2048 + h * 128;
    float x1 = (float)p[lane], x2 = (float)p[lane + 64];
    float c = cosp[s * 64 + lane], si = sinp[s * 64 + lane];
    float r1 = x1 * c + x2 * si;
    float r2 = x2 * c - x1 * si;
    float ss = r1 * r1 + r2 * r2;
#pragma unroll
    for (int msk = 1; msk < 64; msk <<= 1) ss += __shfl_xor(ss, msk);
    float sc = rsqrtf(ss * (1.0f / 128.0f) + 1.1920928955078125e-07f) * 1.2f;
    if (blockIdx.y == 0) sc *= (0.08838834764831845f * 1.4426950408889634f);
    p[lane] = (bf16)(r1 * sc);
    p[lane + 64] = (bf16)(r2 * sc);
}

// ---------------------------------------------------------------------------
// Flash attention fwd, 32x32x16 MFMA, swapped QK^T, P in registers via
// permlane32_swap. 4 waves x 32 q = 128 q/block. KV tile 64.
// K: LDS [64][256B] XOR-swizzled, staged via global_load_lds (pre-swz src).
// V: LDS Vt[128][72] transposed; staged via uint col-pair reads + b128 writes.
__global__ __launch_bounds__(256, 3) void attn_kernel(const bf16* __restrict__ q,
                                                      const bf16* __restrict__ k,
                                                      const bf16* __restrict__ v,
                                                      bf16* __restrict__ y) {
    __shared__ __align__(16) bf16 Ks[64 * 128];
    __shared__ __align__(16) bf16 Vt[128][72];

    const int tid = threadIdx.x, lane = tid & 63, wv = tid >> 6;
    const int q31 = lane & 31, h5 = lane >> 5;

    // bijective XCD-chunked swizzle: XCD c owns bh in {4c..4c+3}
    int wgid = blockIdx.y * 16 + blockIdx.x;
    int xcd = wgid & 7, j = wgid >> 3;
    int bh = xcd * 4 + (j >> 4);
    int qblk = j & 15;
    const int b = bh >> 4, h = bh & 15;
    const int q0 = qblk * 128;

    // Q regs (B-operand): col=q=q31, k=d=ks*16+h5*8+j
    const bf16* qptr = q + (size_t)(b * 2048 + q0 + wv * 32 + q31) * 2048 +
                       h * 128 + h5 * 8;
    bf16x8 qf[8];
#pragma unroll
    for (int ks = 0; ks < 8; ++ks) qf[ks] = *(const bf16x8*)(qptr + ks * 16);

    float mrun = -INFINITY, lrun = 0.f;
    f32x16 acco[4] = {};

    const bf16* vbase = v + (size_t)(b * 2048 + wv * 16) * 2048 + h * 128 + 2 * lane;
    const bf16* kbase = k + (size_t)(b * 2048) * 2048 + h * 128;

    for (int kt = 0; kt < 2048; kt += 64) {
        // ---- K stage: 4 x global_load_lds(16B)/thread, swizzled source
#pragma unroll
        for (int i = 0; i < 4; ++i) {
            int chunk = wv * 4 + i;          // 16 chunks x 1KB (4 rows x 256B)
            int row = chunk * 4 + (lane >> 4);
            int cb = ((lane & 15) * 16) ^ ((row & 7) << 4);
            gload16((const char*)(kbase + (size_t)(kt + row) * 2048) + cb,
                    (char*)Ks + chunk * 1024);
        }
        // ---- V stage: thread owns cols {2*lane, 2*lane+1}, kv rows wv*16..+15
        {
            const bf16* vp = vbase + (size_t)kt * 2048;
            unsigned u[16];
#pragma unroll
            for (int jj = 0; jj < 16; ++jj)
                u[jj] = *(const unsigned*)(vp + (size_t)jj * 2048);
            union { unsigned short s[8]; bf16x8 v8; } r0a, r0b, r1a, r1b;
#pragma unroll
            for (int jj = 0; jj < 8; ++jj) {
                r0a.s[jj] = (unsigned short)(u[jj] & 0xffff);
                r1a.s[jj] = (unsigned short)(u[jj] >> 16);
                r0b.s[jj] = (unsigned short)(u[jj + 8] & 0xffff);
                r1b.s[jj] = (unsigned short)(u[jj + 8] >> 16);
            }
            *(bf16x8*)(&Vt[2 * lane][wv * 16]) = r0a.v8;
            *(bf16x8*)(&Vt[2 * lane][wv * 16 + 8]) = r0b.v8;
            *(bf16x8*)(&Vt[2 * lane + 1][wv * 16]) = r1a.v8;
            *(bf16x8*)(&Vt[2 * lane + 1][wv * 16 + 8]) = r1b.v8;
        }
        __syncthreads();

        // ---- swapped QK^T: st[kvb] = K(32kv x 128d) . Q^T -> S^T[kv][q]
        f32x16 st[2];
        __builtin_amdgcn_s_setprio(1);
#pragma unroll
        for (int kvb = 0; kvb < 2; ++kvb) {
            f32x16 a = {};
#pragma unroll
            for (int ks = 0; ks < 8; ++ks) {
                int row = kvb * 32 + q31;
                int cb = (32 * ks + 16 * h5) ^ ((row & 7) << 4);
                const bf16x8 kf = *(const bf16x8*)((const char*)Ks + row * 256 + cb);
                a = __builtin_amdgcn_mfma_f32_32x32x16_bf16(kf, qf[ks], a, 0, 0, 0);
            }
            st[kvb] = a;
        }
        __builtin_amdgcn_s_setprio(0);

        // ---- online softmax (exp2 domain; scale*log2e folded into q)
        float t8[8];
#pragma unroll
        for (int r = 0; r < 8; ++r)
            t8[r] = fmaxf(fmaxf(st[0][r], st[0][r + 8]),
                          fmaxf(st[1][r], st[1][r + 8]));
        float mx = fmaxf(fmaxf(fmaxf(t8[0], t8[1]), fmaxf(t8[2], t8[3])),
                         fmaxf(fmaxf(t8[4], t8[5]), fmaxf(t8[6], t8[7])));
        mx = fmaxf(mx, __shfl_xor(mx, 32));

        if (__any(mx - mrun > 8.0f)) {   // defer-max: rescale rarely
            float mn = fmaxf(mrun, mx);
            float alpha = exp2f(mrun - mn);
            mrun = mn;
            lrun *= alpha;
#pragma unroll
            for (int r = 0; r < 16; ++r) {
                int qr = (r & 3) + 8 * (r >> 2) + 4 * h5;
                float al = __shfl(alpha, qr);
                acco[0][r] *= al; acco[1][r] *= al;
                acco[2][r] *= al; acco[3][r] *= al;
            }
        }

        unsigned w[2][8];
        float rsa = 0.f, rsb = 0.f;
#pragma unroll
        for (int kvb = 0; kvb < 2; ++kvb)
#pragma unroll
            for (int i = 0; i < 8; ++i) {
                float p0 = exp2f(st[kvb][2 * i] - mrun);
                float p1 = exp2f(st[kvb][2 * i + 1] - mrun);
                if (i & 1) rsb += p0 + p1; else rsa += p0 + p1;
                w[kvb][i] = pk2(p0, p1);
            }
        float rs = rsa + rsb;
        rs += __shfl_xor(rs, 32);
        lrun += rs;

        // ---- PV: A-frags via permlane32_swap, B-frags from Vt
        __builtin_amdgcn_s_setprio(1);
#pragma unroll
        for (int b2 = 0; b2 < 2; ++b2)
#pragma unroll
            for (int ksl = 0; ksl < 2; ++ksl) {
                const int ks = b2 * 2 + ksl, u0 = ksl * 4;
                unsigned f0 = w[b2][u0 + 0], f2 = w[b2][u0 + 2];
                unsigned f1 = w[b2][u0 + 1], f3 = w[b2][u0 + 3];
                plswap(f0, f2);
                plswap(f1, f3);
                union { unsigned uu[4]; bf16x8 v8; } fr;
                fr.uu[0] = f0; fr.uu[1] = f1; fr.uu[2] = f2; fr.uu[3] = f3;
#pragma unroll
                for (int dblk = 0; dblk < 4; ++dblk) {
                    const bf16x8 vf =
                        *(const bf16x8*)(&Vt[dblk * 32 + q31][ks * 16 + h5 * 8]);
                    acco[dblk] = __builtin_amdgcn_mfma_f32_32x32x16_bf16(
                        fr.v8, vf, acco[dblk], 0, 0, 0);
                }
            }
        __builtin_amdgcn_s_setprio(0);
        __syncthreads();
    }

    // epilogue: lane holds O[16 q rows][d=dblk*32+q31]; 1/l from lane qr
    float linv = 1.0f / lrun;
#pragma unroll
    for (int r = 0; r < 16; ++r) {
        int qr = (r & 3) + 8 * (r >> 2) + 4 * h5;
        float il = __shfl(linv, qr);
        size_t row = (size_t)(b * 2048 + q0 + wv * 32 + qr) * 2048 + h * 128;
#pragma unroll
        for (int dblk = 0; dblk < 4; ++dblk)
            y[row + dblk * 32 + q31] = (bf16)(acco[dblk][r] * il);
    }
}

// ---------------------------------------------------------------------------
extern "C" void kernel_launch(void* const* d_in, const int* in_sizes, int n_in,
                              void* d_out, int out_size, void* d_ws, size_t ws_size,
                              hipStream_t stream) {
    const float* x = (const float*)d_in[0];
    const float* cs = (const float*)d_in[1];
    const float* sn = (const float*)d_in[2];
    const float* Wq = (const float*)d_in[3];
    const float* Wk = (const float*)d_in[4];
    const float* Wv = (const float*)d_in[5];
    const float* Wo = (const float*)d_in[6];

    char* ws = (char*)d_ws;
    bf16* xb  = (bf16*)(ws + 0);          // 4096x2048
    bf16* wqb = (bf16*)(ws + 16777216);   // 2048x2048
    bf16* wkb = (bf16*)(ws + 25165824);
    bf16* wvb = (bf16*)(ws + 33554432);
    bf16* wob = (bf16*)(ws + 41943040);
    bf16* qb  = (bf16*)(ws + 50331648);   // 4096x2048
    bf16* kb  = (bf16*)(ws + 67108864);
    bf16* vb  = (bf16*)(ws + 83886080);
    bf16* yb  = (bf16*)(ws + 100663296);

    cvt_kernel<<<1024, 256, 0, stream>>>(x, xb, 8388608 / 8);
    cvt_kernel<<<512, 256, 0, stream>>>(Wq, wqb, 4194304 / 8);
    cvt_kernel<<<512, 256, 0, stream>>>(Wk, wkb, 4194304 / 8);
    cvt_kernel<<<512, 256, 0, stream>>>(Wv, wvb, 4194304 / 8);
    cvt_kernel<<<512, 256, 0, stream>>>(Wo, wob, 4194304 / 8);

    dim3 g(16, 32);  // N/128, M/128
    gemm_bt<false><<<g, 256, 0, stream>>>(xb, wqb, qb, 4096, 2048, 2048);
    gemm_bt<false><<<g, 256, 0, stream>>>(xb, wkb, kb, 4096, 2048, 2048);
    gemm_bt<false><<<g, 256, 0, stream>>>(xb, wvb, vb, 4096, 2048, 2048);

    rope_rms<<<dim3(16384, 2), 256, 0, stream>>>(qb, kb, cs, sn);

    attn_kernel<<<dim3(16, 32), 256, 0, stream>>>(qb, kb, vb, yb);

    gemm_bt<true><<<g, 256, 0, stream>>>(yb, wob, d_out, 4096, 2048, 2048);
}

// Round 4
// 326.723 us; speedup vs baseline: 1.3208x; 1.0565x over previous
//
#include <hip/hip_runtime.h>
#include <hip/hip_bf16.h>
#include <math.h>

typedef __bf16 bf16;
typedef __attribute__((ext_vector_type(8))) __bf16 bf16x8;
typedef __attribute__((ext_vector_type(4))) float f32x4;
typedef __attribute__((ext_vector_type(16))) float f32x16;

#define DEV __device__ __forceinline__

// ---------------------------------------------------------------------------
// async global->LDS, 16B per lane. LDS dest is wave-uniform base + lane*16.
DEV void gload16(const void* g, void* l) {
    __builtin_amdgcn_global_load_lds(
        (__attribute__((address_space(1))) void*)(void*)g,
        (__attribute__((address_space(3))) void*)l, 16, 0, 0);
}

DEV unsigned pk2(float a, float b) {
    union { bf16 h[2]; unsigned u; } z;
    z.h[0] = (bf16)a; z.h[1] = (bf16)b;
    return z.u;
}

// swap a's hi-32-lane contents with b's lo-32-lane contents.
DEV void plswap(unsigned& a, unsigned& b) {
    asm volatile("v_permlane32_swap_b32 %0, %1" : "+v"(a), "+v"(b));
}

// ---------------------------------------------------------------------------
// fp32 -> bf16 conversion, 8 elems/thread, grid-stride
__global__ __launch_bounds__(256) void cvt_kernel(const float* __restrict__ in,
                                                  bf16* __restrict__ out, int n8) {
    for (int i = blockIdx.x * 256 + threadIdx.x; i < n8; i += gridDim.x * 256) {
        const float4* p = (const float4*)(in + (size_t)i * 8);
        float4 a = p[0], b = p[1];
        bf16x8 o;
        o[0] = (bf16)a.x; o[1] = (bf16)a.y; o[2] = (bf16)a.z; o[3] = (bf16)a.w;
        o[4] = (bf16)b.x; o[5] = (bf16)b.y; o[6] = (bf16)b.z; o[7] = (bf16)b.w;
        *(bf16x8*)(out + (size_t)i * 8) = o;
    }
}

// ---------------------------------------------------------------------------
// C[M,N] = A[M,K] @ B[N,K]^T. 128x128 tile, BK=64, 4 waves. (unchanged)
template <bool F32OUT>
__global__ __launch_bounds__(256) void gemm_bt(const bf16* __restrict__ A,
                                               const bf16* __restrict__ B,
                                               void* __restrict__ Cout,
                                               int M, int N, int K) {
    __shared__ __align__(16) bf16 As[128 * 64];
    __shared__ __align__(16) bf16 Bs[128 * 64];
    const int tid = threadIdx.x, lane = tid & 63, wv = tid >> 6;
    const int tm = blockIdx.y * 128, tn = blockIdx.x * 128;
    const int wr = (wv >> 1) * 64, wc = (wv & 1) * 64;

    f32x4 acc[4][4] = {};
    const int scb = (lane & 7) * 16;

    for (int k0 = 0; k0 < K; k0 += 64) {
#pragma unroll
        for (int i = 0; i < 4; ++i) {
            int chunk = wv * 4 + i;
            int row = chunk * 8 + (lane >> 3);
            int cb = scb ^ ((row & 7) << 4);
            gload16((const char*)(A + (size_t)(tm + row) * K + k0) + cb,
                    (char*)As + chunk * 1024);
            gload16((const char*)(B + (size_t)(tn + row) * K + k0) + cb,
                    (char*)Bs + chunk * 1024);
        }
        __syncthreads();
#pragma unroll
        for (int kk = 0; kk < 2; ++kk) {
            bf16x8 af[4], bfr[4];
#pragma unroll
            for (int m = 0; m < 4; ++m) {
                int row = wr + m * 16 + (lane & 15);
                int cb = (kk * 64 + ((lane >> 4) * 16)) ^ ((row & 7) << 4);
                af[m] = *(const bf16x8*)((const char*)As + row * 128 + cb);
            }
#pragma unroll
            for (int n = 0; n < 4; ++n) {
                int row = wc + n * 16 + (lane & 15);
                int cb = (kk * 64 + ((lane >> 4) * 16)) ^ ((row & 7) << 4);
                bfr[n] = *(const bf16x8*)((const char*)Bs + row * 128 + cb);
            }
#pragma unroll
            for (int m = 0; m < 4; ++m)
#pragma unroll
                for (int n = 0; n < 4; ++n)
                    acc[m][n] = __builtin_amdgcn_mfma_f32_16x16x32_bf16(
                        af[m], bfr[n], acc[m][n], 0, 0, 0);
        }
        __syncthreads();
    }
#pragma unroll
    for (int m = 0; m < 4; ++m)
#pragma unroll
        for (int n = 0; n < 4; ++n)
#pragma unroll
            for (int r = 0; r < 4; ++r) {
                int row = tm + wr + m * 16 + (lane >> 4) * 4 + r;
                int col = tn + wc + n * 16 + (lane & 15);
                if (F32OUT)
                    ((float*)Cout)[(size_t)row * N + col] = acc[m][n][r];
                else
                    ((bf16*)Cout)[(size_t)row * N + col] = (bf16)acc[m][n][r];
            }
}

// ---------------------------------------------------------------------------
// RoPE + RMSNorm(*1.2), in-place. q pre-scaled by (1/sqrt(128))*log2(e).
__global__ __launch_bounds__(256) void rope_rms(bf16* __restrict__ q,
                                                bf16* __restrict__ k,
                                                const float* __restrict__ cosp,
                                                const float* __restrict__ sinp) {
    int gw = blockIdx.x * 4 + (threadIdx.x >> 6);
    int lane = threadIdx.x & 63;
    bf16* base = (blockIdx.y == 0) ? q : k;
    int m = gw >> 4, h = gw & 15;
    int s = m & 2047;
    bf16* p = base + (size_t)m * 2048 + h * 128;
    float x1 = (float)p[lane], x2 = (float)p[lane + 64];
    float c = cosp[s * 64 + lane], si = sinp[s * 64 + lane];
    float r1 = x1 * c + x2 * si;
    float r2 = x2 * c - x1 * si;
    float ss = r1 * r1 + r2 * r2;
#pragma unroll
    for (int msk = 1; msk < 64; msk <<= 1) ss += __shfl_xor(ss, msk);
    float sc = rsqrtf(ss * (1.0f / 128.0f) + 1.1920928955078125e-07f) * 1.2f;
    if (blockIdx.y == 0) sc *= (0.08838834764831845f * 1.4426950408889634f);
    p[lane] = (bf16)(r1 * sc);
    p[lane + 64] = (bf16)(r2 * sc);
}

// ---------------------------------------------------------------------------
// Flash attention fwd, 32x32x16 MFMA, swapped QK^T, P in registers via
// permlane32_swap. 4 waves x 32 q = 128 q/block. KV tile 64.
// DOUBLE-BUFFERED 2-phase pipeline: next tile's K gload_lds + V reg-loads are
// issued before this tile's compute; V repack+ds_write after compute; one
// barrier per tile.
__global__ __launch_bounds__(256, 2) void attn_kernel(const bf16* __restrict__ q,
                                                      const bf16* __restrict__ k,
                                                      const bf16* __restrict__ v,
                                                      bf16* __restrict__ y) {
    __shared__ __align__(16) bf16 Ks[2][64 * 128];
    __shared__ __align__(16) bf16 Vt[2][128][72];

    const int tid = threadIdx.x, lane = tid & 63, wv = tid >> 6;
    const int q31 = lane & 31, h5 = lane >> 5;

    // bijective XCD-chunked swizzle: XCD c owns bh in {4c..4c+3}
    int wgid = blockIdx.y * 16 + blockIdx.x;
    int xcd = wgid & 7, j = wgid >> 3;
    int bh = xcd * 4 + (j >> 4);
    int qblk = j & 15;
    const int b = bh >> 4, h = bh & 15;
    const int q0 = qblk * 128;

    // Q regs (B-operand): col=q=q31, k=d=ks*16+h5*8+j
    const bf16* qptr = q + (size_t)(b * 2048 + q0 + wv * 32 + q31) * 2048 +
                       h * 128 + h5 * 8;
    bf16x8 qf[8];
#pragma unroll
    for (int ks = 0; ks < 8; ++ks) qf[ks] = *(const bf16x8*)(qptr + ks * 16);

    float mrun = -INFINITY, lrun = 0.f;
    f32x16 acco[4] = {};

    const bf16* vbase = v + (size_t)(b * 2048 + wv * 16) * 2048 + h * 128 + 2 * lane;
    const bf16* kbase = k + (size_t)(b * 2048) * 2048 + h * 128;

    unsigned u[16];  // in-flight V tile (reg-staged)

    auto stageK = [&](int t, int buf) {
#pragma unroll
        for (int i = 0; i < 4; ++i) {
            int chunk = wv * 4 + i;          // 16 chunks x 1KB (4 rows x 256B)
            int row = chunk * 4 + (lane >> 4);
            int cb = ((lane & 15) * 16) ^ ((row & 7) << 4);
            gload16((const char*)(kbase + (size_t)(t * 64 + row) * 2048) + cb,
                    (char*)(Ks[buf]) + chunk * 1024);
        }
    };
    auto loadV = [&](int t) {
        const bf16* vp = vbase + (size_t)(t * 64) * 2048;
#pragma unroll
        for (int jj = 0; jj < 16; ++jj)
            u[jj] = *(const unsigned*)(vp + (size_t)jj * 2048);
    };
    auto writeV = [&](int buf) {
        union { unsigned short s[8]; bf16x8 v8; } r0a, r0b, r1a, r1b;
#pragma unroll
        for (int jj = 0; jj < 8; ++jj) {
            r0a.s[jj] = (unsigned short)(u[jj] & 0xffff);
            r1a.s[jj] = (unsigned short)(u[jj] >> 16);
            r0b.s[jj] = (unsigned short)(u[jj + 8] & 0xffff);
            r1b.s[jj] = (unsigned short)(u[jj + 8] >> 16);
        }
        *(bf16x8*)(&Vt[buf][2 * lane][wv * 16]) = r0a.v8;
        *(bf16x8*)(&Vt[buf][2 * lane][wv * 16 + 8]) = r0b.v8;
        *(bf16x8*)(&Vt[buf][2 * lane + 1][wv * 16]) = r1a.v8;
        *(bf16x8*)(&Vt[buf][2 * lane + 1][wv * 16 + 8]) = r1b.v8;
    };

    // prologue: stage tile 0 into buffer 0
    stageK(0, 0);
    loadV(0);
    writeV(0);
    __syncthreads();

    for (int t = 0; t < 32; ++t) {
        const int c = t & 1;
        // issue next tile's loads early — they fly across this tile's compute
        if (t < 31) {
            stageK(t + 1, c ^ 1);
            loadV(t + 1);
        }

        // ---- swapped QK^T: st[kvb] = K(32kv x 128d) . Q^T -> S^T[kv][q]
        f32x16 st[2];
        __builtin_amdgcn_s_setprio(1);
#pragma unroll
        for (int kvb = 0; kvb < 2; ++kvb) {
            f32x16 a = {};
#pragma unroll
            for (int ks = 0; ks < 8; ++ks) {
                int row = kvb * 32 + q31;
                int cb = (32 * ks + 16 * h5) ^ ((row & 7) << 4);
                const bf16x8 kf =
                    *(const bf16x8*)((const char*)(Ks[c]) + row * 256 + cb);
                a = __builtin_amdgcn_mfma_f32_32x32x16_bf16(kf, qf[ks], a, 0, 0, 0);
            }
            st[kvb] = a;
        }
        __builtin_amdgcn_s_setprio(0);

        // ---- online softmax (exp2 domain; scale*log2e folded into q)
        float t8[8];
#pragma unroll
        for (int r = 0; r < 8; ++r)
            t8[r] = fmaxf(fmaxf(st[0][r], st[0][r + 8]),
                          fmaxf(st[1][r], st[1][r + 8]));
        float mx = fmaxf(fmaxf(fmaxf(t8[0], t8[1]), fmaxf(t8[2], t8[3])),
                         fmaxf(fmaxf(t8[4], t8[5]), fmaxf(t8[6], t8[7])));
        mx = fmaxf(mx, __shfl_xor(mx, 32));

        if (__any(mx - mrun > 8.0f)) {   // defer-max: rescale rarely
            float mn = fmaxf(mrun, mx);
            float alpha = exp2f(mrun - mn);
            mrun = mn;
            lrun *= alpha;
#pragma unroll
            for (int r = 0; r < 16; ++r) {
                int qr = (r & 3) + 8 * (r >> 2) + 4 * h5;
                float al = __shfl(alpha, qr);
                acco[0][r] *= al; acco[1][r] *= al;
                acco[2][r] *= al; acco[3][r] *= al;
            }
        }

        unsigned w[2][8];
        float rsa = 0.f, rsb = 0.f;
#pragma unroll
        for (int kvb = 0; kvb < 2; ++kvb)
#pragma unroll
            for (int i = 0; i < 8; ++i) {
                float p0 = exp2f(st[kvb][2 * i] - mrun);
                float p1 = exp2f(st[kvb][2 * i + 1] - mrun);
                if (i & 1) rsb += p0 + p1; else rsa += p0 + p1;
                w[kvb][i] = pk2(p0, p1);
            }
        float rs = rsa + rsb;
        rs += __shfl_xor(rs, 32);
        lrun += rs;

        // ---- PV: A-frags via permlane32_swap, B-frags from Vt[c]
        __builtin_amdgcn_s_setprio(1);
#pragma unroll
        for (int b2 = 0; b2 < 2; ++b2)
#pragma unroll
            for (int ksl = 0; ksl < 2; ++ksl) {
                const int ks = b2 * 2 + ksl, u0 = ksl * 4;
                unsigned f0 = w[b2][u0 + 0], f2 = w[b2][u0 + 2];
                unsigned f1 = w[b2][u0 + 1], f3 = w[b2][u0 + 3];
                plswap(f0, f2);
                plswap(f1, f3);
                union { unsigned uu[4]; bf16x8 v8; } fr;
                fr.uu[0] = f0; fr.uu[1] = f1; fr.uu[2] = f2; fr.uu[3] = f3;
#pragma unroll
                for (int dblk = 0; dblk < 4; ++dblk) {
                    const bf16x8 vf = *(const bf16x8*)(
                        &Vt[c][dblk * 32 + q31][ks * 16 + h5 * 8]);
                    acco[dblk] = __builtin_amdgcn_mfma_f32_32x32x16_bf16(
                        fr.v8, vf, acco[dblk], 0, 0, 0);
                }
            }
        __builtin_amdgcn_s_setprio(0);

        // ---- late half of next-tile V staging (loads have landed by now)
        if (t < 31) writeV(c ^ 1);
        __syncthreads();
    }

    // epilogue: lane holds O[16 q rows][d=dblk*32+q31]; 1/l from lane qr
    float linv = 1.0f / lrun;
#pragma unroll
    for (int r = 0; r < 16; ++r) {
        int qr = (r & 3) + 8 * (r >> 2) + 4 * h5;
        float il = __shfl(linv, qr);
        size_t row = (size_t)(b * 2048 + q0 + wv * 32 + qr) * 2048 + h * 128;
#pragma unroll
        for (int dblk = 0; dblk < 4; ++dblk)
            y[row + dblk * 32 + q31] = (bf16)(acco[dblk][r] * il);
    }
}

// ---------------------------------------------------------------------------
extern "C" void kernel_launch(void* const* d_in, const int* in_sizes, int n_in,
                              void* d_out, int out_size, void* d_ws, size_t ws_size,
                              hipStream_t stream) {
    const float* x = (const float*)d_in[0];
    const float* cs = (const float*)d_in[1];
    const float* sn = (const float*)d_in[2];
    const float* Wq = (const float*)d_in[3];
    const float* Wk = (const float*)d_in[4];
    const float* Wv = (const float*)d_in[5];
    const float* Wo = (const float*)d_in[6];

    char* ws = (char*)d_ws;
    bf16* xb  = (bf16*)(ws + 0);          // 4096x2048
    bf16* wqb = (bf16*)(ws + 16777216);   // 2048x2048
    bf16* wkb = (bf16*)(ws + 25165824);
    bf16* wvb = (bf16*)(ws + 33554432);
    bf16* wob = (bf16*)(ws + 41943040);
    bf16* qb  = (bf16*)(ws + 50331648);   // 4096x2048
    bf16* kb  = (bf16*)(ws + 67108864);
    bf16* vb  = (bf16*)(ws + 83886080);
    bf16* yb  = (bf16*)(ws + 100663296);

    cvt_kernel<<<1024, 256, 0, stream>>>(x, xb, 8388608 / 8);
    cvt_kernel<<<512, 256, 0, stream>>>(Wq, wqb, 4194304 / 8);
    cvt_kernel<<<512, 256, 0, stream>>>(Wk, wkb, 4194304 / 8);
    cvt_kernel<<<512, 256, 0, stream>>>(Wv, wvb, 4194304 / 8);
    cvt_kernel<<<512, 256, 0, stream>>>(Wo, wob, 4194304 / 8);

    dim3 g(16, 32);  // N/128, M/128
    gemm_bt<false><<<g, 256, 0, stream>>>(xb, wqb, qb, 4096, 2048, 2048);
    gemm_bt<false><<<g, 256, 0, stream>>>(xb, wkb, kb, 4096, 2048, 2048);
    gemm_bt<false><<<g, 256, 0, stream>>>(xb, wvb, vb, 4096, 2048, 2048);

    rope_rms<<<dim3(16384, 2), 256, 0, stream>>>(qb, kb, cs, sn);

    attn_kernel<<<dim3(16, 32), 256, 0, stream>>>(qb, kb, vb, yb);

    gemm_bt<true><<<g, 256, 0, stream>>>(yb, wob, d_out, 4096, 2048, 2048);
}